// Round 2
// baseline (4841.475 us; speedup 1.0000x reference)
//
#include <hip/hip_runtime.h>
#include <stdint.h>

#define B_    128
#define T_    64
#define E_    300
#define EPAD  384
#define H_    2048
#define KH    2048
#define KTOT  2432
#define NCHUNK 19
#define NWG   256
#define NTHR  512

typedef unsigned short u16;
typedef short bf8 __attribute__((ext_vector_type(8)));
typedef float f4 __attribute__((ext_vector_type(4)));

__device__ __forceinline__ u16 f2b(float f) {
    uint32_t u = __float_as_uint(f);
    u += 0x7fffu + ((u >> 16) & 1u);   // round-to-nearest-even
    return (u16)(u >> 16);
}
__device__ __forceinline__ float sigm(float x) { return 1.f / (1.f + __expf(-x)); }
__device__ __forceinline__ float tanh_(float x) {
    float xx = fminf(fmaxf(x, -15.f), 15.f);
    float e = __expf(2.f * xx);
    return (e - 1.f) / (e + 1.f);
}

// ---- prep: weight conversion + zero-init (runs every launch; resets barrier) ----
__global__ void prep_kernel(const float* __restrict__ w_hh, const float* __restrict__ w_ih,
                            const float* __restrict__ b_ih, const float* __restrict__ b_hh,
                            u16* __restrict__ w_hh_b, u16* __restrict__ w_ih_b,
                            float* __restrict__ bsum, u16* __restrict__ h_b0,
                            unsigned* __restrict__ bar) {
    int tid = blockIdx.x * blockDim.x + threadIdx.x;
    int np = gridDim.x * blockDim.x;
    if (tid == 0) *bar = 0u;
    for (int i = tid; i < 4 * H_ * H_; i += np) w_hh_b[i] = f2b(w_hh[i]);
    for (int i = tid; i < 4 * H_ * EPAD; i += np) {
        int n = i / EPAD, k = i - n * EPAD;
        w_ih_b[i] = (k < E_) ? f2b(w_ih[n * E_ + k]) : (u16)0;
    }
    for (int i = tid; i < 4 * H_; i += np) bsum[i] = b_ih[i] + b_hh[i];
    for (int i = tid; i < B_ * H_; i += np) h_b0[i] = 0;
}

// ---- embedding gather -> bf16 padded rows [t*B+b][EPAD] ----
__global__ void gather_kernel(const int* __restrict__ input, const float* __restrict__ embed,
                              u16* __restrict__ x_b) {
    int r = blockIdx.x;                 // r = t*B + b
    int t = r >> 7, b = r & 127;
    int row = input[b * T_ + t];
    const float* src = embed + (size_t)row * E_;
    u16* dst = x_b + (size_t)r * EPAD;
    for (int e = threadIdx.x; e < EPAD; e += blockDim.x)
        dst[e] = (e < E_) ? f2b(src[e]) : (u16)0;
}

// ---- persistent weight-stationary LSTM: 256 WGs x 512 thr, all 64 steps ----
// WG wg owns 8 hidden cols j0=wg*8, all 4 gates -> 32 W-rows, n-local = 4*jj + g.
// Wave wid owns K-chunks {wid, wid+8, wid+16} of 19 (128 k each), all 32 n, all 128 m.
// B(weights) stationary in VGPRs (<=96). K-loop: A-frags global->VGPR, no LDS, no barriers.
// Epilogue: 8-way partial reduction via LDS in 4 m-phases + fused cell; c lives in LDS.
__global__ __launch_bounds__(NTHR, 2) void
lstm_persist(const u16* __restrict__ xb, const u16* __restrict__ whh,
             const u16* __restrict__ wih, const float* __restrict__ bsum,
             u16* __restrict__ h0, u16* __restrict__ h1,
             unsigned* __restrict__ bar, float* __restrict__ outp) {
    __shared__ float bufs[8][32][35];   // [kp][m-local][n-local(32)+3 pad] : 35 KB
    __shared__ float cst[B_][8];        // c-state [m][jj] : 4 KB
    int tid = threadIdx.x;
    int wid = tid >> 6, lane = tid & 63;
    int l15 = lane & 15, q = lane >> 4;
    int wg = blockIdx.x;
    int j0 = wg * 8;

    // ---- load stationary weight fragments (MFMA A-operand: row=l15 -> n, k=q*8..) ----
    bf8 Bf[3][4][2];
#pragma unroll
    for (int i = 0; i < 3; ++i) {
        int c = wid + 8 * i;
        if (c < NCHUNK) {
#pragma unroll
            for (int kf = 0; kf < 4; ++kf)
#pragma unroll
                for (int nt = 0; nt < 2; ++nt) {
                    int nl = nt * 16 + l15;
                    int g = nl & 3, jj = nl >> 2;          // gate-minor row permutation
                    size_t ng = (size_t)g * H_ + j0 + jj;
                    int k = c * 128 + kf * 32 + q * 8;
                    const u16* src = (c < 16) ? (whh + ng * KH + k)
                                              : (wih + ng * EPAD + (k - KH));
                    Bf[i][kf][nt] = *(const bf8*)src;
                }
        }
    }
    int nch = (wid + 16 < NCHUNK) ? 3 : 2;

    // cell-thread statics (threads 0..255 handle cells)
    int cjj = tid & 7, cml = (tid >> 3) & 31;
    float bs[4];
#pragma unroll
    for (int g = 0; g < 4; ++g) bs[g] = bsum[g * H_ + j0 + cjj];
    for (int i = tid; i < B_ * 8; i += NTHR) ((float*)cst)[i] = 0.f;
    __syncthreads();

    for (int t = 0; t < T_; ++t) {
        const u16* hin = (t & 1) ? h1 : h0;
        u16* hout      = (t & 1) ? h0 : h1;
        const u16* xt = xb + (size_t)t * B_ * EPAD;

        f4 acc[2][8];
#pragma unroll
        for (int nt = 0; nt < 2; ++nt)
#pragma unroll
            for (int mt = 0; mt < 8; ++mt) acc[nt][mt] = (f4)0.f;

        // ---- K-loop: barrier-free, LDS-free; A-frags direct global->VGPR ----
#pragma unroll
        for (int i = 0; i < 3; ++i) {
            if (i < nch) {
                int c = wid + 8 * i;
                const u16* base;
                int rs;
                if (c < 16) { base = hin + c * 128; rs = KH; }
                else        { base = xt + (c - 16) * 128; rs = EPAD; }
                const u16* lp = base + (size_t)l15 * rs + q * 8;
                bf8 a0[4], a1[4];
#pragma unroll
                for (int kf = 0; kf < 4; ++kf) a0[kf] = *(const bf8*)(lp + kf * 32);
#pragma unroll
                for (int mt = 0; mt < 8; ++mt) {
                    const bf8* cur = (mt & 1) ? a1 : a0;
                    bf8* nxt = (mt & 1) ? a0 : a1;
                    if (mt < 7) {
                        const u16* lpn = lp + (size_t)(mt + 1) * 16 * rs;
#pragma unroll
                        for (int kf = 0; kf < 4; ++kf) nxt[kf] = *(const bf8*)(lpn + kf * 32);
                    }
#pragma unroll
                    for (int kf = 0; kf < 4; ++kf) {
                        acc[0][mt] = __builtin_amdgcn_mfma_f32_16x16x32_bf16(
                            Bf[i][kf][0], cur[kf], acc[0][mt], 0, 0, 0);
                        acc[1][mt] = __builtin_amdgcn_mfma_f32_16x16x32_bf16(
                            Bf[i][kf][1], cur[kf], acc[1][mt], 0, 0, 0);
                    }
                }
            }
        }

        // ---- epilogue: 4 m-phases of (write partials -> reduce -> cell) ----
        bool last = (t == T_ - 1);
#pragma unroll
        for (int p = 0; p < 4; ++p) {
            __syncthreads();            // bufs free (prev phase consumers done)
#pragma unroll
            for (int mh = 0; mh < 2; ++mh) {
                int mt = p * 2 + mh;
                int ml = mh * 16 + l15;
#pragma unroll
                for (int nt = 0; nt < 2; ++nt)
                    *(f4*)&bufs[wid][ml][nt * 16 + q * 4] = acc[nt][mt];
            }
            __syncthreads();
            if (tid < 256) {
                int m = p * 32 + cml;
                float s0 = 0.f, s1 = 0.f, s2 = 0.f, s3 = 0.f;
#pragma unroll
                for (int kp = 0; kp < 8; ++kp) {
                    f4 v = *(const f4*)&bufs[kp][cml][4 * cjj];
                    s0 += v[0]; s1 += v[1]; s2 += v[2]; s3 += v[3];
                }
                float iv = sigm(s0 + bs[0]);
                float fv = sigm(s1 + bs[1]);
                float gv = tanh_(s2 + bs[2]);
                float ov = sigm(s3 + bs[3]);
                float cn = fv * cst[m][cjj] + iv * gv;
                cst[m][cjj] = cn;
                float hn = ov * tanh_(cn);
                hout[(size_t)m * H_ + j0 + cjj] = f2b(hn);
                if (last) outp[(size_t)m * H_ + j0 + cjj] = hn;
            }
        }

        // ---- grid barrier (device-scope, monotonic counter) ----
        __threadfence();
        __syncthreads();
        if (tid == 0) {
            __hip_atomic_fetch_add(bar, 1u, __ATOMIC_RELEASE, __HIP_MEMORY_SCOPE_AGENT);
            unsigned tgt = (unsigned)(t + 1) * NWG;
            while (__hip_atomic_load(bar, __ATOMIC_RELAXED, __HIP_MEMORY_SCOPE_AGENT) < tgt)
                __builtin_amdgcn_s_sleep(1);
            (void)__hip_atomic_load(bar, __ATOMIC_ACQUIRE, __HIP_MEMORY_SCOPE_AGENT);
        }
        __syncthreads();
    }
}

extern "C" void kernel_launch(void* const* d_in, const int* in_sizes, int n_in,
                              void* d_out, int out_size, void* d_ws, size_t ws_size,
                              hipStream_t stream) {
    const int*   input = (const int*)d_in[0];
    const float* embed = (const float*)d_in[1];
    const float* w_ih  = (const float*)d_in[2];
    const float* w_hh  = (const float*)d_in[3];
    const float* b_ih  = (const float*)d_in[4];
    const float* b_hh  = (const float*)d_in[5];
    float* out = (float*)d_out;

    char* ws = (char*)d_ws;
    size_t o = 0;
    u16* w_hh_b = (u16*)(ws + o); o += (size_t)4 * H_ * H_ * 2;     // 33.5 MB
    u16* w_ih_b = (u16*)(ws + o); o += (size_t)4 * H_ * EPAD * 2;   // 6.3 MB
    u16* x_b    = (u16*)(ws + o); o += (size_t)B_ * T_ * EPAD * 2;  // 6.3 MB
    float* bsum = (float*)(ws + o); o += (size_t)4 * H_ * 4;
    u16* h_b0   = (u16*)(ws + o); o += (size_t)B_ * H_ * 2;
    u16* h_b1   = (u16*)(ws + o); o += (size_t)B_ * H_ * 2;
    o = (o + 255) & ~(size_t)255;
    unsigned* bar = (unsigned*)(ws + o); o += 256;

    prep_kernel<<<1024, 256, 0, stream>>>(w_hh, w_ih, b_ih, b_hh,
                                          w_hh_b, w_ih_b, bsum, h_b0, bar);
    gather_kernel<<<B_ * T_, 64, 0, stream>>>(input, embed, x_b);

    void* kargs[] = {(void*)&x_b, (void*)&w_hh_b, (void*)&w_ih_b, (void*)&bsum,
                     (void*)&h_b0, (void*)&h_b1, (void*)&bar, (void*)&out};
    hipLaunchCooperativeKernel((void*)lstm_persist, dim3(NWG), dim3(NTHR),
                               kargs, 0, stream);
}

// Round 3
// 1127.068 us; speedup vs baseline: 4.2956x; 4.2956x over previous
//
#include <hip/hip_runtime.h>
#include <stdint.h>

#define H_    2048
#define B_    128
#define T_    64
#define E_    300
#define NKU   76        // K units of 32: 64 for h (2048) + 12 for x (384 padded)
#define XGRP  48        // 384/8 x-groups per timestep
#define NWG   256
#define NTHR  512

typedef unsigned short u16;
typedef uint32_t u32;
typedef short bf8 __attribute__((ext_vector_type(8)));
typedef float f4 __attribute__((ext_vector_type(4)));

__device__ __forceinline__ u16 f2b(float f) {
    u32 u = __float_as_uint(f);
    u += 0x7fffu + ((u >> 16) & 1u);   // round-to-nearest-even
    return (u16)(u >> 16);
}
__device__ __forceinline__ float sigm(float x) { return 1.f / (1.f + __expf(-x)); }
__device__ __forceinline__ float tanh_(float x) {
    float xx = fminf(fmaxf(x, -15.f), 15.f);
    float e = __expf(2.f * xx);
    return (e - 1.f) / (e + 1.f);
}

// ---- prep: pack weights into per-wave MFMA fragment order, pack biases, zero state ----
// wP frag id f = ((wg*76 + ku)*2 + nt)*64 + lane ; 8 u16 per lane (16B).
// element: n_local = nt*16 + (lane&15) -> g = n&3 (gate-minor), jj = n>>2 ;
//          k = ku*32 + (lane>>4)*8 + j ; row = g*H + wg*8 + jj.
__global__ void prep_kernel(const float* __restrict__ w_hh, const float* __restrict__ w_ih,
                            const float* __restrict__ b_ih, const float* __restrict__ b_hh,
                            u16* __restrict__ wP, float* __restrict__ bsP,
                            float* __restrict__ cP, u16* __restrict__ hP0) {
    int tid = blockIdx.x * blockDim.x + threadIdx.x;
    int np = gridDim.x * blockDim.x;
    const int NF = NWG * NKU * 2 * 64;
    for (int f = tid; f < NF; f += np) {
        int lane = f & 63;
        int fr = f >> 6;
        int nt = fr & 1;
        int rest = fr >> 1;
        int ku = rest % NKU;
        int wg = rest / NKU;
        int l15 = lane & 15, q = lane >> 4;
        int nl = nt * 16 + l15;
        int g = nl & 3, jj = nl >> 2;
        int ng = g * H_ + wg * 8 + jj;
        int k0 = ku * 32 + q * 8;
        union { u16 s[8]; uint4 v; } tmp;
#pragma unroll
        for (int j = 0; j < 8; ++j) {
            int k = k0 + j;
            float v;
            if (k < H_) v = w_hh[(size_t)ng * H_ + k];
            else { int kx = k - H_; v = (kx < E_) ? w_ih[(size_t)ng * E_ + kx] : 0.f; }
            tmp.s[j] = f2b(v);
        }
        *(uint4*)&wP[(size_t)f * 8] = tmp.v;
    }
    // packed bias: bsP[wg*32 + jj*4 + g]
    for (int n = tid; n < 4 * H_; n += np) {
        int wg = n >> 5, nl = n & 31;
        int jj = nl >> 2, g = nl & 3;
        int src = g * H_ + wg * 8 + jj;
        bsP[n] = b_ih[src] + b_hh[src];
    }
    // zero c-state (packed [wg][m][8] fp32) and h0 (packed [grp][m][8] bf16)
    for (int i = tid; i < NWG * B_ * 8; i += np) cP[i] = 0.f;
    for (int i = tid; i < (H_ / 8) * B_ * 8 / 2; i += np) ((u32*)hP0)[i] = 0u;
}

// ---- embedding gather -> packed bf16 xP[t][gx][b][8] ----
__global__ void gather_kernel(const int* __restrict__ input, const float* __restrict__ embed,
                              u16* __restrict__ xP) {
    int t = blockIdx.x;
    u16* xt = xP + (size_t)t * XGRP * B_ * 8;
    for (int id = threadIdx.x; id < XGRP * B_; id += blockDim.x) {
        int b = id & (B_ - 1);
        int gx = id >> 7;
        int row = input[b * T_ + t];
        const float* src = embed + (size_t)row * E_;
        union { u16 s[8]; uint4 v; } tmp;
#pragma unroll
        for (int j = 0; j < 8; ++j) {
            int k = gx * 8 + j;
            tmp.s[j] = (k < E_) ? f2b(src[k]) : (u16)0;
        }
        *(uint4*)&xt[(size_t)id * 8] = tmp.v;   // id = gx*128 + b
    }
}

// ---- one LSTM step: 256 WGs (wg = 8 hidden cols x 4 gates), 512 thr ----
// Wave wid owns a contiguous K-slice (10 or 9 units of 32) over all 128 m.
// K-loop: zero LDS, zero barriers; frags double-buffered global->VGPR.
// Epilogue: 8-way cross-wave LDS reduction in 4 m-phases + fused cell.
__global__ __launch_bounds__(NTHR) void
step_kernel(const u16* __restrict__ wP, const float* __restrict__ bsP,
            const u16* __restrict__ xt, const u16* __restrict__ hin,
            u16* __restrict__ hout, float* __restrict__ cP,
            float* __restrict__ outp) {
    __shared__ float bufs[8][32][36];   // [wave][m-local][n-local 32 + 4 pad] = 36 KB
    int tid = threadIdx.x;
    int wid = tid >> 6, lane = tid & 63;
    int l15 = lane & 15, q = lane >> 4;
    int wg = blockIdx.x;

    int cnt = (wid < 4) ? 10 : 9;
    int ks  = (wid < 4) ? wid * 10 : 40 + (wid - 4) * 9;

    const u16* wbase = wP + (size_t)wg * NKU * 1024 + lane * 8;
    int hoff = q * 1024 + l15 * 8;

    f4 acc[2][8];
#pragma unroll
    for (int nt = 0; nt < 2; ++nt)
#pragma unroll
        for (int mt = 0; mt < 8; ++mt) acc[nt][mt] = (f4)0.f;

#define LDF(KU, WF, HB) do {                                                  \
        int ku_ = (KU);                                                       \
        const u16* wb_ = wbase + (size_t)ku_ * 1024;                          \
        WF[0] = *(const bf8*)wb_;                                             \
        WF[1] = *(const bf8*)(wb_ + 512);                                     \
        const u16* hb_ = ((ku_ < 64) ? (hin + (size_t)ku_ * 4096)             \
                                     : (xt + (size_t)(ku_ - 64) * 4096)) + hoff; \
        _Pragma("unroll")                                                     \
        for (int mt_ = 0; mt_ < 8; ++mt_) HB[mt_] = *(const bf8*)(hb_ + mt_ * 128); \
    } while (0)

#define MM(WF, HB) do {                                                       \
        _Pragma("unroll")                                                     \
        for (int mt_ = 0; mt_ < 8; ++mt_) {                                   \
            acc[0][mt_] = __builtin_amdgcn_mfma_f32_16x16x32_bf16(WF[0], HB[mt_], acc[0][mt_], 0, 0, 0); \
            acc[1][mt_] = __builtin_amdgcn_mfma_f32_16x16x32_bf16(WF[1], HB[mt_], acc[1][mt_], 0, 0, 0); \
        }                                                                     \
    } while (0)

    bf8 wfA[2], hbA[8], wfB[2], hbB[8];
    LDF(ks, wfA, hbA);
    int i = 0;
    while (true) {
        if (i + 1 < cnt) LDF(ks + i + 1, wfB, hbB);
        MM(wfA, hbA);
        if (i + 1 >= cnt) break;
        if (i + 2 < cnt) LDF(ks + i + 2, wfA, hbA);
        MM(wfB, hbB);
        if (i + 2 >= cnt) break;
        i += 2;
    }
#undef LDF
#undef MM

    // ---- epilogue ----
    int cjj = tid & 7, cml = (tid >> 3) & 31;
    f4 bsv = {0.f, 0.f, 0.f, 0.f};
    if (tid < 256) bsv = *(const f4*)&bsP[wg * 32 + cjj * 4];
#pragma unroll
    for (int p = 0; p < 4; ++p) {
        __syncthreads();                       // prev phase consumers done
#pragma unroll
        for (int mh = 0; mh < 2; ++mh) {
            int mt = p * 2 + mh;
            int ml = mh * 16 + l15;
            *(f4*)&bufs[wid][ml][q * 4]      = acc[0][mt];   // n-local = q*4+r
            *(f4*)&bufs[wid][ml][16 + q * 4] = acc[1][mt];   // n-local = 16+q*4+r
        }
        __syncthreads();
        if (tid < 256) {
            int m = p * 32 + cml;
            f4 s = {0.f, 0.f, 0.f, 0.f};
#pragma unroll
            for (int kp = 0; kp < 8; ++kp) {
                f4 v = *(const f4*)&bufs[kp][cml][cjj * 4];
                s[0] += v[0]; s[1] += v[1]; s[2] += v[2]; s[3] += v[3];
            }
            float iv = sigm(s[0] + bsv[0]);
            float fv = sigm(s[1] + bsv[1]);
            float gv = tanh_(s[2] + bsv[2]);
            float ov = sigm(s[3] + bsv[3]);
            size_t ci = ((size_t)wg * B_ + m) * 8 + cjj;     // packed layout
            float cn = fv * cP[ci] + iv * gv;
            cP[ci] = cn;
            float hn = ov * tanh_(cn);
            hout[ci] = f2b(hn);                              // hout group index == wg
            if (outp) outp[(size_t)m * H_ + wg * 8 + cjj] = hn;
        }
    }
}

extern "C" void kernel_launch(void* const* d_in, const int* in_sizes, int n_in,
                              void* d_out, int out_size, void* d_ws, size_t ws_size,
                              hipStream_t stream) {
    const int*   input = (const int*)d_in[0];
    const float* embed = (const float*)d_in[1];
    const float* w_ih  = (const float*)d_in[2];
    const float* w_hh  = (const float*)d_in[3];
    const float* b_ih  = (const float*)d_in[4];
    const float* b_hh  = (const float*)d_in[5];
    float* out = (float*)d_out;

    char* ws = (char*)d_ws;
    size_t o = 0;
    u16* wP   = (u16*)(ws + o); o += (size_t)NWG * NKU * 2 * 64 * 8 * 2;  // 39.85 MB
    u16* xP   = (u16*)(ws + o); o += (size_t)T_ * XGRP * B_ * 8 * 2;      // 6.29 MB
    u16* hP0  = (u16*)(ws + o); o += (size_t)(H_ / 8) * B_ * 8 * 2;       // 512 KB
    u16* hP1  = (u16*)(ws + o); o += (size_t)(H_ / 8) * B_ * 8 * 2;       // 512 KB
    float* cP = (float*)(ws + o); o += (size_t)NWG * B_ * 8 * 4;          // 1 MB
    float* bsP = (float*)(ws + o); o += (size_t)4 * H_ * 4;               // 32 KB

    prep_kernel<<<2048, 256, 0, stream>>>(w_hh, w_ih, b_ih, b_hh, wP, bsP, cP, hP0);
    gather_kernel<<<T_, 256, 0, stream>>>(input, embed, xP);

    for (int t = 0; t < T_; ++t) {
        const u16* hin = (t & 1) ? hP1 : hP0;
        u16* hout      = (t & 1) ? hP0 : hP1;
        float* hof     = (t == T_ - 1) ? out : nullptr;
        step_kernel<<<NWG, NTHR, 0, stream>>>(
            wP, bsP, xP + (size_t)t * XGRP * B_ * 8, hin, hout, cP, hof);
    }
}

// Round 4
// 1074.027 us; speedup vs baseline: 4.5078x; 1.0494x over previous
//
#include <hip/hip_runtime.h>
#include <stdint.h>

#define H_    2048
#define B_    128
#define T_    64
#define E_    300
#define NKU   76        // K units of 32: 64 for h (2048) + 12 for x (384 padded)
#define XGRP  48        // 384/8 x-groups per timestep
#define NWG   256
#define NTHR  512
#define NJG   128       // j-groups of 16 hidden cols

typedef unsigned short u16;
typedef uint32_t u32;
typedef short bf8 __attribute__((ext_vector_type(8)));
typedef float f4 __attribute__((ext_vector_type(4)));

__device__ __forceinline__ u16 f2b(float f) {
    u32 u = __float_as_uint(f);
    u += 0x7fffu + ((u >> 16) & 1u);   // round-to-nearest-even
    return (u16)(u >> 16);
}
__device__ __forceinline__ float sigm(float x) { return 1.f / (1.f + __expf(-x)); }
__device__ __forceinline__ float tanh_(float x) {
    float xx = fminf(fmaxf(x, -15.f), 15.f);
    float e = __expf(2.f * xx);
    return (e - 1.f) / (e + 1.f);
}

// ---- prep: pack weights into per-wave MFMA fragment order, pack biases, zero state ----
// frag id fr = (jg*76 + ku)*4 + nt ; lane 0..63 holds 8 u16 (16B).
// element: n_local = nt*16 + (lane&15) -> g = n&3 (gate-minor), jj = n>>2 (0..15);
//          k = ku*32 + (lane>>4)*8 + j ; w-row = g*H + jg*16 + jj.
__global__ void prep_kernel(const float* __restrict__ w_hh, const float* __restrict__ w_ih,
                            const float* __restrict__ b_ih, const float* __restrict__ b_hh,
                            u16* __restrict__ wP, float* __restrict__ bsP,
                            float* __restrict__ cP, u16* __restrict__ hP0) {
    int tid = blockIdx.x * blockDim.x + threadIdx.x;
    int np = gridDim.x * blockDim.x;
    const int NF = NJG * NKU * 4 * 64;
    for (int f = tid; f < NF; f += np) {
        int lane = f & 63;
        int fr = f >> 6;
        int nt = fr & 3;
        int rest = fr >> 2;
        int ku = rest % NKU;
        int jg = rest / NKU;
        int l15 = lane & 15, q = lane >> 4;
        int nl = nt * 16 + l15;
        int g = nl & 3, jj = nl >> 2;
        int ng = g * H_ + jg * 16 + jj;
        int k0 = ku * 32 + q * 8;
        union { u16 s[8]; uint4 v; } tmp;
#pragma unroll
        for (int j = 0; j < 8; ++j) {
            int k = k0 + j;
            float v;
            if (k < H_) v = w_hh[(size_t)ng * H_ + k];
            else { int kx = k - H_; v = (kx < E_) ? w_ih[(size_t)ng * E_ + kx] : 0.f; }
            tmp.s[j] = f2b(v);
        }
        *(uint4*)&wP[(size_t)f * 8] = tmp.v;
    }
    // packed bias: bsP[jg*64 + jj*4 + g]
    for (int n = tid; n < NJG * 64; n += np) {
        int jg = n >> 6, r = n & 63;
        int jj = r >> 2, g = r & 3;
        int src = g * H_ + jg * 16 + jj;
        bsP[n] = b_ih[src] + b_hh[src];
    }
    // zero c-state (packed [jg][m][16] fp32) and h0 (packed [kg8][m][8] bf16)
    for (int i = tid; i < NJG * B_ * 16; i += np) cP[i] = 0.f;
    for (int i = tid; i < (H_ / 8) * B_ * 8 / 2; i += np) ((u32*)hP0)[i] = 0u;
}

// ---- embedding gather -> packed bf16 xP[t][gx][b][8] ----
__global__ void gather_kernel(const int* __restrict__ input, const float* __restrict__ embed,
                              u16* __restrict__ xP) {
    int t = blockIdx.x;
    u16* xt = xP + (size_t)t * XGRP * B_ * 8;
    for (int id = threadIdx.x; id < XGRP * B_; id += blockDim.x) {
        int b = id & (B_ - 1);
        int gx = id >> 7;
        int row = input[b * T_ + t];
        const float* src = embed + (size_t)row * E_;
        union { u16 s[8]; uint4 v; } tmp;
#pragma unroll
        for (int j = 0; j < 8; ++j) {
            int k = gx * 8 + j;
            tmp.s[j] = (k < E_) ? f2b(src[k]) : (u16)0;
        }
        *(uint4*)&xt[(size_t)id * 8] = tmp.v;   // id = gx*128 + b
    }
}

// ---- one LSTM step: 256 WGs = 128 j-groups x 2 m-halves, 512 thr ----
// blockIdx swizzle: jg = bid&127, wgm = bid>>7  (both m-halves of jg on same XCD).
// Wave wid owns a contiguous K-slice (10 or 9 ku of 32) x full 64n x 64m tile:
// per ku 8 loads -> 32 MFMA. Triple-buffered (prefetch depth 2), no LDS/barriers in K-loop.
// Epilogue: 8-way cross-wave LDS reduction in 4 m-phases + fused cell; c packed in global.
__global__ __launch_bounds__(NTHR) void
step_kernel(const u16* __restrict__ wP, const float* __restrict__ bsP,
            const u16* __restrict__ xt, const u16* __restrict__ hin,
            u16* __restrict__ hout, float* __restrict__ cP,
            float* __restrict__ outp) {
    __shared__ float bufs[8][16][68];   // [wave][m-local 16][n 64 + 4 pad] = 34 KB
    int tid = threadIdx.x;
    int wid = tid >> 6, lane = tid & 63;
    int l15 = lane & 15, q = lane >> 4;
    int jg  = blockIdx.x & 127;
    int wgm = blockIdx.x >> 7;

    int cnt = (wid < 4) ? 10 : 9;
    int ks  = (wid < 4) ? wid * 10 : 40 + (wid - 4) * 9;

    const u16* wbase = wP + (size_t)jg * NKU * 2048 + lane * 8;
    int hoff = q * 1024 + wgm * 512 + l15 * 8;

    f4 acc[4][4];
#pragma unroll
    for (int nt = 0; nt < 4; ++nt)
#pragma unroll
        for (int mt = 0; mt < 4; ++mt) acc[nt][mt] = (f4)0.f;

#define LDF(KU, WF, HB) do {                                                  \
        int ku_ = (KU);                                                       \
        const u16* wb_ = wbase + (size_t)ku_ * 2048;                          \
        WF[0] = *(const bf8*)(wb_);                                           \
        WF[1] = *(const bf8*)(wb_ + 512);                                     \
        WF[2] = *(const bf8*)(wb_ + 1024);                                    \
        WF[3] = *(const bf8*)(wb_ + 1536);                                    \
        const u16* hb_ = ((ku_ < 64) ? (hin + (size_t)ku_ * 4096)             \
                                     : (xt + (size_t)(ku_ - 64) * 4096)) + hoff; \
        HB[0] = *(const bf8*)(hb_);                                           \
        HB[1] = *(const bf8*)(hb_ + 128);                                     \
        HB[2] = *(const bf8*)(hb_ + 256);                                     \
        HB[3] = *(const bf8*)(hb_ + 384);                                     \
    } while (0)

#define MM(WF, HB) do {                                                       \
        _Pragma("unroll")                                                     \
        for (int nt_ = 0; nt_ < 4; ++nt_)                                     \
            _Pragma("unroll")                                                 \
            for (int mt_ = 0; mt_ < 4; ++mt_)                                 \
                acc[nt_][mt_] = __builtin_amdgcn_mfma_f32_16x16x32_bf16(      \
                    WF[nt_], HB[mt_], acc[nt_][mt_], 0, 0, 0);                \
    } while (0)

    bf8 wA[4], hA[4], wB[4], hB[4], wC[4], hC[4];
    LDF(ks, wA, hA);
    LDF(ks + 1, wB, hB);
    int i = 0;
    while (true) {
        if (i + 2 < cnt) LDF(ks + i + 2, wC, hC);
        MM(wA, hA);
        if (i + 1 >= cnt) break;
        if (i + 3 < cnt) LDF(ks + i + 3, wA, hA);
        MM(wB, hB);
        if (i + 2 >= cnt) break;
        if (i + 4 < cnt) LDF(ks + i + 4, wB, hB);
        MM(wC, hC);
        if (i + 3 >= cnt) break;
        i += 3;
    }
#undef LDF
#undef MM

    // ---- epilogue: 4 m-phases (16 m each) of write partials -> reduce -> cell ----
    int jj = tid & 15, ml16 = (tid >> 4) & 15;
    f4 bsv = {0.f, 0.f, 0.f, 0.f};
    if (tid < 256) bsv = *(const f4*)&bsP[jg * 64 + jj * 4];
#pragma unroll
    for (int p = 0; p < 4; ++p) {
        __syncthreads();                       // prev phase consumers done
        // D layout: col(lane&15) = m-local, row(q*4+r) = n-local within nt
        *(f4*)&bufs[wid][l15][0 * 16 + q * 4] = acc[0][p];
        *(f4*)&bufs[wid][l15][1 * 16 + q * 4] = acc[1][p];
        *(f4*)&bufs[wid][l15][2 * 16 + q * 4] = acc[2][p];
        *(f4*)&bufs[wid][l15][3 * 16 + q * 4] = acc[3][p];
        __syncthreads();
        if (tid < 256) {
            f4 s = {0.f, 0.f, 0.f, 0.f};
#pragma unroll
            for (int w = 0; w < 8; ++w) {
                f4 v = *(const f4*)&bufs[w][ml16][jj * 4];
                s[0] += v[0]; s[1] += v[1]; s[2] += v[2]; s[3] += v[3];
            }
            float iv = sigm(s[0] + bsv[0]);
            float fv = sigm(s[1] + bsv[1]);
            float gv = tanh_(s[2] + bsv[2]);
            float ov = sigm(s[3] + bsv[3]);
            int m = wgm * 64 + p * 16 + ml16;
            size_t ci = ((size_t)jg * B_ + m) * 16 + jj;     // packed private c
            float cn = fv * cP[ci] + iv * gv;
            cP[ci] = cn;
            float hn = ov * tanh_(cn);
            int jglob = jg * 16 + jj;
            hout[(size_t)(jglob >> 3) * 1024 + m * 8 + (jglob & 7)] = f2b(hn);
            if (outp) outp[(size_t)m * H_ + jglob] = hn;
        }
    }
}

extern "C" void kernel_launch(void* const* d_in, const int* in_sizes, int n_in,
                              void* d_out, int out_size, void* d_ws, size_t ws_size,
                              hipStream_t stream) {
    const int*   input = (const int*)d_in[0];
    const float* embed = (const float*)d_in[1];
    const float* w_ih  = (const float*)d_in[2];
    const float* w_hh  = (const float*)d_in[3];
    const float* b_ih  = (const float*)d_in[4];
    const float* b_hh  = (const float*)d_in[5];
    float* out = (float*)d_out;

    char* ws = (char*)d_ws;
    size_t o = 0;
    u16* wP   = (u16*)(ws + o); o += (size_t)NJG * NKU * 4 * 64 * 8 * 2;  // 39.85 MB
    u16* xP   = (u16*)(ws + o); o += (size_t)T_ * XGRP * B_ * 8 * 2;      // 6.29 MB
    u16* hP0  = (u16*)(ws + o); o += (size_t)(H_ / 8) * B_ * 8 * 2;       // 512 KB
    u16* hP1  = (u16*)(ws + o); o += (size_t)(H_ / 8) * B_ * 8 * 2;       // 512 KB
    float* cP = (float*)(ws + o); o += (size_t)NJG * B_ * 16 * 4;         // 1 MB
    float* bsP = (float*)(ws + o); o += (size_t)4 * H_ * 4;               // 32 KB

    prep_kernel<<<2048, 256, 0, stream>>>(w_hh, w_ih, b_ih, b_hh, wP, bsP, cP, hP0);
    gather_kernel<<<T_, 256, 0, stream>>>(input, embed, xP);

    for (int t = 0; t < T_; ++t) {
        const u16* hin = (t & 1) ? hP1 : hP0;
        u16* hout      = (t & 1) ? hP0 : hP1;
        float* hof     = (t == T_ - 1) ? out : nullptr;
        step_kernel<<<NWG, NTHR, 0, stream>>>(
            wP, bsP, xP + (size_t)t * XGRP * B_ * 8, hin, hout, cP, hof);
    }
}